// Round 7
// baseline (93.390 us; speedup 1.0000x reference)
//
#include <hip/hip_runtime.h>

typedef float f32x4 __attribute__((ext_vector_type(4)));
typedef short s16x8 __attribute__((ext_vector_type(8)));
typedef unsigned short u16x8 __attribute__((ext_vector_type(8)));
typedef unsigned int u32;

// ---------- helpers ----------
__device__ __forceinline__ unsigned short f2bf(float f) {
  u32 x = __float_as_uint(f);
  u32 r = (x + 0x7fffu + ((x >> 16) & 1u)) >> 16;  // RNE
  return (unsigned short)r;
}

__device__ __forceinline__ void gload16(const void* g, void* lds) {
  // global -> LDS direct copy, 16B per lane, LDS dest = wave-uniform base + lane*16
  __builtin_amdgcn_global_load_lds(
      (const __attribute__((address_space(1))) u32*)(uintptr_t)g,
      (__attribute__((address_space(3))) u32*)(u32)(uintptr_t)lds,
      16, 0, 0);
}

// ---------- pack A: [X | c_prev] -> bf16, tiled (128 rows x 64 k), chunk-swizzled ----------
// A_t tile (RB, KS) at byte offset (RB*16+KS)*16384; element (r, k') at
// r*128 + ((chunk ^ (r&7))<<4) + (k'%8)*2, chunk = k'/8.
__global__ __launch_bounds__(256) void pack_a_kernel(const float* __restrict__ X,
                                                     const float* __restrict__ C,
                                                     unsigned short* __restrict__ At) {
  int idx = blockIdx.x * 256 + threadIdx.x;  // one thread per 16B chunk; 2,097,152 total
  int row = idx >> 7;
  int kc = idx & 127;  // global k-chunk 0..127 (k = kc*8)
  const float* src = (kc < 64) ? (X + row * 512 + kc * 8)
                               : (C + row * 512 + (kc - 64) * 8);
  float4 v0 = *(const float4*)src;
  float4 v1 = *(const float4*)(src + 4);
  u16x8 h;
  h[0] = f2bf(v0.x); h[1] = f2bf(v0.y); h[2] = f2bf(v0.z); h[3] = f2bf(v0.w);
  h[4] = f2bf(v1.x); h[5] = f2bf(v1.y); h[6] = f2bf(v1.z); h[7] = f2bf(v1.w);
  int tile = ((row >> 7) << 4) + (kc >> 3);
  int r = row & 127, c = kc & 7;
  char* dst = (char*)At + (size_t)tile * 16384 + r * 128 + ((c ^ (r & 7)) << 4);
  *(u16x8*)dst = h;
}

// ---------- pack B: W/U columns -> B_t[n][k] bf16, gate-interleaved, tiled+swizzled ----------
// n = (j/16)*64 + g*16 + (j%16); B_t tile (NB, KS) at (NB*16+KS)*16384, same swizzle as A.
__global__ __launch_bounds__(256) void pack_b_kernel(
    const float* __restrict__ Wf, const float* __restrict__ Wi,
    const float* __restrict__ Wo, const float* __restrict__ Wc,
    const float* __restrict__ Uf, const float* __restrict__ Ui,
    const float* __restrict__ Uo, const float* __restrict__ Uc,
    unsigned short* __restrict__ Bt) {
  __shared__ float T[64][68];  // 64k x 64j tile, padded
  int bid = blockIdx.x;        // 512 blocks: 4 gates x 8 j-tiles x 16 k-tiles
  int kt = bid & 15;
  int jt = (bid >> 4) & 7;
  int g = bid >> 7;
  const float* Wg = (g == 0) ? Wf : (g == 1) ? Wi : (g == 2) ? Wo : Wc;
  const float* Ug = (g == 0) ? Uf : (g == 1) ? Ui : (g == 2) ? Uo : Uc;
  const float* srcbase = (kt < 8) ? (Wg + (size_t)kt * 64 * 512)
                                  : (Ug + (size_t)(kt - 8) * 64 * 512);
  int j0 = jt * 64;
  int tid = threadIdx.x;
  int kk = tid >> 2, q = tid & 3;  // 4 threads per k-row, 16 floats each
  const float* rp = srcbase + (size_t)kk * 512 + j0 + q * 16;
  float4 a = *(const float4*)(rp);
  float4 b = *(const float4*)(rp + 4);
  float4 c4 = *(const float4*)(rp + 8);
  float4 d = *(const float4*)(rp + 12);
  *(float4*)&T[kk][q * 16] = a;
  *(float4*)&T[kk][q * 16 + 4] = b;
  *(float4*)&T[kk][q * 16 + 8] = c4;
  *(float4*)&T[kk][q * 16 + 12] = d;
  __syncthreads();
  for (int ci = tid; ci < 512; ci += 256) {  // 64 j x 8 chunks
    int jj = ci >> 3, c = ci & 7;
    u16x8 h;
#pragma unroll
    for (int e = 0; e < 8; ++e) h[e] = f2bf(T[c * 8 + e][jj]);
    int j = j0 + jj;
    int n = ((j >> 4) << 6) + (g << 4) + (j & 15);
    int NB = n >> 7, r = n & 127;
    char* dst = (char*)Bt + (size_t)(NB * 16 + kt) * 16384 + r * 128 +
                ((c ^ (r & 7)) << 4);
    *(u16x8*)dst = h;
  }
}

// ---------- fused GEMM + LSTM epilogue (256x128 tile, 8 waves, R1 loop body) ----------
// Block: BM=256 x BN=128, 512 threads = 8 waves (4m x 2n), each wave 64x64 out.
// LDS 48 KiB (A 32K = two 128-row units, B 16K) -> 2 blocks/CU (VGPR-capped at
// 124 regs) = 16 waves/CU vs R1's 12; per-thread staging 6 gload16/K-step vs 8;
// grid 1024 = exactly 2 residency rounds (no tail). Loop body is R1's verbatim
// (bulk-load 16 frags then 32 MFMA — best scheduler input measured).
__global__ __launch_bounds__(512, 4) void gemm_fused(
    const unsigned short* __restrict__ At, const unsigned short* __restrict__ Bt,
    const float* __restrict__ c_prev,
    const float* __restrict__ bf_, const float* __restrict__ bi_,
    const float* __restrict__ bo_, const float* __restrict__ bc_,
    float* __restrict__ H) {
  __shared__ __align__(16) char As[32768];
  __shared__ __align__(16) char Bs[16384];
  int bid = blockIdx.x;
  int wg = (bid & 7) * 128 + (bid >> 3);  // XCD-aware swizzle (1024 % 8 == 0)
  int bn = wg & 15, bm = wg >> 4;         // 16 n-blocks x 64 m-blocks
  int tid = threadIdx.x;
  int lane = tid & 63, w = tid >> 6;
  int wr = w >> 1, wc = w & 1;            // 4 m-waves x 2 n-waves
  int l15 = lane & 15, kq = lane >> 4;

  // A row-units 2bm and 2bm+1 (each 128 rows x 1024 k, 16 KiB per K-step)
  const char* gA0 = (const char*)At + (size_t)(2 * bm) * (16 * 16384) + tid * 16;
  const char* gA1 = (const char*)At + (size_t)(2 * bm + 1) * (16 * 16384) + tid * 16;
  const char* gB = (const char*)Bt + (size_t)bn * (16 * 16384) + tid * 16;

  f32x4 acc[4][4] = {};

  int aoff[4][2], boff[4][2];
#pragma unroll
  for (int m = 0; m < 4; ++m) {
    int r = wr * 64 + m * 16 + l15;              // 0..255
    int base = (r & 128) ? 16384 : 0;            // second staged unit for rows >=128
    int rl = r & 127;
    aoff[m][0] = base + rl * 128 + (((kq) ^ (rl & 7)) << 4);
    aoff[m][1] = base + rl * 128 + (((kq + 4) ^ (rl & 7)) << 4);
  }
#pragma unroll
  for (int n = 0; n < 4; ++n) {
    int r = wc * 64 + n * 16 + l15;              // 0..127 packed-n within block
    boff[n][0] = r * 128 + (((kq) ^ (r & 7)) << 4);
    boff[n][1] = r * 128 + (((kq + 4) ^ (r & 7)) << 4);
  }

  for (int ks = 0; ks < 16; ++ks) {
    __syncthreads();
    {
      int o = ks * 16384;
      gload16(gA0 + o, As + tid * 16);
      gload16(gA0 + o + 8192, As + tid * 16 + 8192);
      gload16(gA1 + o, As + 16384 + tid * 16);
      gload16(gA1 + o + 8192, As + 16384 + tid * 16 + 8192);
      gload16(gB + o, Bs + tid * 16);
      gload16(gB + o + 8192, Bs + tid * 16 + 8192);
    }
    __syncthreads();
    s16x8 a[4][2], b[4][2];
#pragma unroll
    for (int m = 0; m < 4; ++m) {
      a[m][0] = *(const s16x8*)(As + aoff[m][0]);
      a[m][1] = *(const s16x8*)(As + aoff[m][1]);
    }
#pragma unroll
    for (int n = 0; n < 4; ++n) {
      b[n][0] = *(const s16x8*)(Bs + boff[n][0]);
      b[n][1] = *(const s16x8*)(Bs + boff[n][1]);
    }
#pragma unroll
    for (int m = 0; m < 4; ++m)
#pragma unroll
      for (int n = 0; n < 4; ++n) {
        acc[m][n] = __builtin_amdgcn_mfma_f32_16x16x32_bf16(a[m][0], b[n][0], acc[m][n], 0, 0, 0);
        acc[m][n] = __builtin_amdgcn_mfma_f32_16x16x32_bf16(a[m][1], b[n][1], acc[m][n], 0, 0, 0);
      }
  }

  // epilogue: acc[m][g] = pre-activation of gate g for (row, j), lane-local
  int j = (bn * 2 + wc) * 16 + l15;
  float vbf = bf_[j], vbi = bi_[j], vbo = bo_[j], vbc = bc_[j];
  int row0 = bm * 256 + wr * 64 + kq * 4;
#pragma unroll
  for (int m = 0; m < 4; ++m) {
#pragma unroll
    for (int ri = 0; ri < 4; ++ri) {
      int row = row0 + m * 16 + ri;
      float fp = acc[m][0][ri] + vbf;
      float ip = acc[m][1][ri] + vbi;
      float op = acc[m][2][ri] + vbo;
      float cq = acc[m][3][ri] + vbc;
      float ft = 1.0f / (1.0f + __expf(-fp));
      float it = 1.0f / (1.0f + __expf(-ip));
      float ot = 1.0f / (1.0f + __expf(-op));
      float ch = 1.0f - 2.0f / (1.0f + __expf(2.0f * cq));
      float cp = c_prev[(size_t)row * 512 + j];
      float ct = ft * cp + it * ch;
      float th = 1.0f - 2.0f / (1.0f + __expf(2.0f * ct));
      H[(size_t)row * 512 + j] = ot * th;
    }
  }
}

extern "C" void kernel_launch(void* const* d_in, const int* in_sizes, int n_in,
                              void* d_out, int out_size, void* d_ws, size_t ws_size,
                              hipStream_t stream) {
  const float* X = (const float*)d_in[0];
  const float* Cp = (const float*)d_in[1];
  const float* Wf = (const float*)d_in[2];
  const float* Wi = (const float*)d_in[3];
  const float* Wo = (const float*)d_in[4];
  const float* Wc = (const float*)d_in[5];
  const float* Uf = (const float*)d_in[6];
  const float* Ui = (const float*)d_in[7];
  const float* Uo = (const float*)d_in[8];
  const float* Uc = (const float*)d_in[9];
  const float* bfp = (const float*)d_in[10];
  const float* bip = (const float*)d_in[11];
  const float* bop = (const float*)d_in[12];
  const float* bcp = (const float*)d_in[13];
  float* H = (float*)d_out;

  unsigned short* At = (unsigned short*)d_ws;                       // 33,554,432 B
  unsigned short* Bt = (unsigned short*)((char*)d_ws + 33554432u);  //  4,194,304 B

  pack_a_kernel<<<8192, 256, 0, stream>>>(X, Cp, At);
  pack_b_kernel<<<512, 256, 0, stream>>>(Wf, Wi, Wo, Wc, Uf, Ui, Uo, Uc, Bt);
  gemm_fused<<<1024, 512, 0, stream>>>(At, Bt, Cp, bfp, bip, bop, bcp, H);
}